// Round 22
// baseline (159.362 us; speedup 1.0000x reference)
//
#include <hip/hip_runtime.h>

#define DIM 192
#define NB 8
#define NTOK 1024
#define HEADS 16
#define DH 64
#define INNER 1024
#define ROWS (NB * NTOK)  // 8192

typedef __bf16 bf16x8 __attribute__((ext_vector_type(8)));
typedef float f32x4 __attribute__((ext_vector_type(4)));
typedef float f32x16 __attribute__((ext_vector_type(16)));
typedef unsigned int u32x4 __attribute__((ext_vector_type(4)));

__device__ inline unsigned short f2bf(float f) {
    union { float f; unsigned u; } v; v.f = f;
    unsigned r = v.u + 0x7FFF + ((v.u >> 16) & 1);
    return (unsigned short)(r >> 16);
}

__device__ inline unsigned pk2(float a, float b) {
    __bf16 x = (__bf16)a, y = (__bf16)b;
    unsigned short ux = __builtin_bit_cast(unsigned short, x);
    unsigned short uy = __builtin_bit_cast(unsigned short, y);
    return (unsigned)ux | ((unsigned)uy << 16);
}

// fragment-major index for a [*][depth] bf16 operand consumed as 32x32x16
__device__ inline size_t fragIdx(int row, int k, int depth) {
    return ((size_t)(row >> 5) * ((size_t)depth * 4) +
            (size_t)(((k >> 4) * 2 + ((k >> 3) & 1)) * 32 + (row & 31))) * 8 + (k & 7);
}

// ---------------- fused preprocessing ----------------
__global__ __launch_bounds__(256) void k_pre(
    const float* __restrict__ x, const float* __restrict__ shift,
    const float* __restrict__ scale, const float* __restrict__ nw,
    const float* __restrict__ nb, const float* __restrict__ wqkv,
    const float* __restrict__ wout,
    unsigned short* __restrict__ hF, unsigned short* __restrict__ wF,
    unsigned short* __restrict__ woF) {
    int bid = blockIdx.x;
    if (bid < 2048) {
        int row = bid * 4 + (threadIdx.x >> 6);
        int lane = threadIdx.x & 63;
        const float* xr = x + row * DIM;
        float v0 = xr[lane], v1 = xr[lane + 64], v2 = xr[lane + 128];
        float s = v0 + v1 + v2;
        #pragma unroll
        for (int m = 1; m < 64; m <<= 1) s += __shfl_xor(s, m);
        float mean = s * (1.0f / DIM);
        float d0 = v0 - mean, d1 = v1 - mean, d2 = v2 - mean;
        float q = d0 * d0 + d1 * d1 + d2 * d2;
        #pragma unroll
        for (int m = 1; m < 64; m <<= 1) q += __shfl_xor(q, m);
        float rs = rsqrtf(q * (1.0f / DIM) + 1e-5f);
        int b = row >> 10;
        float vv[3] = {v0, v1, v2};
        #pragma unroll
        for (int i = 0; i < 3; i++) {
            int d = lane + 64 * i;
            float val = (vv[i] - mean) * rs * nw[d] + nb[d];
            val = val * (1.0f + scale[b * DIM + d]) + shift[b * DIM + d];
            hF[fragIdx(row, d, DIM)] = f2bf(val);
        }
    } else if (bid < 4352) {
        int idx = (bid - 2048) * 256 + threadIdx.x;  // < 192*3072
        int k = idx / 3072, c = idx % 3072;
        wF[fragIdx(c, k, DIM)] = f2bf(wqkv[idx]);
    } else {
        int idx = (bid - 4352) * 256 + threadIdx.x;  // < 1024*192
        int k = idx / 192, c = idx % 192;
        woF[fragIdx(c, k, INNER)] = f2bf(wout[idx]);
    }
}

// ---------------- QKV GEMM v5: fragment-major in AND out ----------------
__global__ __launch_bounds__(256, 3) void k_qkv(
    const unsigned short* __restrict__ hF, const unsigned short* __restrict__ wF,
    unsigned short* __restrict__ qmF, unsigned short* __restrict__ kmF,
    unsigned short* __restrict__ vtF) {
    const float QSC = 0.125f * 1.4426950408889634f;
    int tid = threadIdx.x;
    int wave = tid >> 6, lane = tid & 63;
    int l31 = lane & 31, hi = lane >> 5;
    int c0 = blockIdx.x * 64 + (wave >> 1) * 32;
    int typ = c0 >> 10;              // 0=Q 1=K 2=V
    int hd  = (c0 & 1023) >> 6;      // head
    int coff = c0 & 32;              // 32-channel tile within head panel

    const unsigned short* Ab = wF + (size_t)(c0 >> 5) * 768 * 8;
    bf16x8 af[12];
    #pragma unroll
    for (int kc = 0; kc < 12; kc++)
        af[kc] = *(const bf16x8*)(Ab + ((kc * 2 + hi) * 32 + l31) * 8);

    #pragma unroll
    for (int ns = 0; ns < 2; ns++) {
        int n0 = blockIdx.y * 128 + (wave & 1) * 64 + ns * 32;
        const unsigned short* Bb = hF + (size_t)(n0 >> 5) * 768 * 8;
        f32x16 acc0, acc1;
        #pragma unroll
        for (int r = 0; r < 16; r++) { acc0[r] = 0.f; acc1[r] = 0.f; }
        if (typ < 2) {
            #pragma unroll
            for (int kc = 0; kc < 6; kc++) {
                bf16x8 bf0 = *(const bf16x8*)(Bb + (((2 * kc) * 2 + hi) * 32 + l31) * 8);
                bf16x8 bf1 = *(const bf16x8*)(Bb + (((2 * kc + 1) * 2 + hi) * 32 + l31) * 8);
                acc0 = __builtin_amdgcn_mfma_f32_32x32x16_bf16(af[2 * kc], bf0, acc0, 0, 0, 0);
                acc1 = __builtin_amdgcn_mfma_f32_32x32x16_bf16(af[2 * kc + 1], bf1, acc1, 0, 0, 0);
            }
        } else {
            // V: swap operands so D-lane = channel (d), D-regs = token (n)
            #pragma unroll
            for (int kc = 0; kc < 6; kc++) {
                bf16x8 bf0 = *(const bf16x8*)(Bb + (((2 * kc) * 2 + hi) * 32 + l31) * 8);
                bf16x8 bf1 = *(const bf16x8*)(Bb + (((2 * kc + 1) * 2 + hi) * 32 + l31) * 8);
                acc0 = __builtin_amdgcn_mfma_f32_32x32x16_bf16(bf0, af[2 * kc], acc0, 0, 0, 0);
                acc1 = __builtin_amdgcn_mfma_f32_32x32x16_bf16(bf1, af[2 * kc + 1], acc1, 0, 0, 0);
            }
        }
        f32x16 acc;
        #pragma unroll
        for (int r = 0; r < 16; r++) acc[r] = acc0[r] + acc1[r];

        int bb = n0 >> 10, nm = n0 & 1023;
        int tt = nm >> 6;
        unsigned short* base;
        if (typ == 0) base = qmF + (size_t)(bb * 16 + hd) * 65536;
        else if (typ == 1) base = kmF + (size_t)(bb * 16 + hd) * 65536;
        else base = vtF + (size_t)(bb * 16 + hd) * 65536;

        if (typ < 2) {
            float sc = (typ == 0) ? QSC : 1.0f;
            int rowgrp = (nm >> 5) & 1;
            #pragma unroll
            for (int rg = 0; rg < 4; rg++) {
                int ob = coff + rg * 8;   // d-octet base
                int g = (rowgrp * 4 + (ob >> 4)) * 2 + ((ob >> 3) & 1);
                uint2 val;
                val.x = pk2(acc[rg * 4 + 0] * sc, acc[rg * 4 + 1] * sc);
                val.y = pk2(acc[rg * 4 + 2] * sc, acc[rg * 4 + 3] * sc);
                *(uint2*)(base + (tt * 16 + g) * 256 + l31 * 8 + hi * 4) = val;
            }
        } else {
            int drg = coff >> 5;
            #pragma unroll
            for (int rg = 0; rg < 4; rg++) {
                int nb2 = (nm & 32) + rg * 8;  // n-octet base within tile
                int g = (drg * 4 + (nb2 >> 4)) * 2 + ((nb2 >> 3) & 1);
                uint2 val;
                val.x = pk2(acc[rg * 4 + 0], acc[rg * 4 + 1]);
                val.y = pk2(acc[rg * 4 + 2], acc[rg * 4 + 3]);
                *(uint2*)(base + (tt * 16 + g) * 256 + l31 * 8 + hi * 4) = val;
            }
        }
    }
}

// ---------------- flash attention v14: v12 + unroll-2 scheduling window ----------------
// grid (128 bh, 8 qt) x 256 thr (4 waves). LDS-free fragment-major reads;
// zero-max softmax; QK(t)+PV(t-1) register pipeline. #pragma unroll 2 widens
// the scheduler window across two iterations (cross-iteration interleave of
// QK(t+1) MFMAs under exp(t) VALU is legal: no barriers, fresh C0/C1 per
// iter, real reg usage ~128/512). Unlike r16, no hand-forced state.
__global__ __launch_bounds__(256, 3) void k_attn(
    const unsigned short* __restrict__ qmF, const unsigned short* __restrict__ kmF,
    const unsigned short* __restrict__ vtF, unsigned short* __restrict__ attnF) {
    int tid = threadIdx.x;
    int wave = tid >> 6, lane = tid & 63;
    int l31 = lane & 31, hi = lane >> 5;
    int bh = blockIdx.x, qt = blockIdx.y;
    int qbase = qt * 128 + wave * 32;
    const unsigned short* Qb = qmF + (size_t)bh * 65536;
    const unsigned short* Kb = kmF + (size_t)bh * 65536;
    const unsigned short* Vb = vtF + (size_t)bh * 65536;

    int tq = qbase >> 6, rq = (qbase >> 5) & 1;
    bf16x8 qf[4];
    #pragma unroll
    for (int c = 0; c < 4; c++)
        qf[c] = *(const bf16x8*)(Qb + (tq * 16 + (rq * 4 + c) * 2 + hi) * 256 + l31 * 8);

    float lsum = 0.f;
    f32x16 accO[2];
    #pragma unroll
    for (int r = 0; r < 16; r++) { accO[0][r] = 0.f; accO[1][r] = 0.f; }

    auto ldKf = [&](int t, int rowgrp, int c) -> bf16x8 {
        return *(const bf16x8*)(Kb + (t * 16 + (rowgrp * 4 + c) * 2 + hi) * 256 + l31 * 8);
    };
    auto ldVf = [&](int t, int dt, int nc) -> bf16x8 {
        return *(const bf16x8*)(Vb + (t * 16 + (dt * 4 + nc) * 2 + hi) * 256 + l31 * 8);
    };
    auto packP = [&](const f32x16& P, bf16x8& w0, bf16x8& w1) {
        u32x4 A, B;
        {
            auto r0 = __builtin_amdgcn_permlane32_swap(pk2(P[0], P[1]), pk2(P[4], P[5]), false, false);
            auto r1 = __builtin_amdgcn_permlane32_swap(pk2(P[2], P[3]), pk2(P[6], P[7]), false, false);
            A[0] = r0[0]; A[1] = r1[0]; A[2] = r0[1]; A[3] = r1[1];
        }
        {
            auto r0 = __builtin_amdgcn_permlane32_swap(pk2(P[8], P[9]), pk2(P[12], P[13]), false, false);
            auto r1 = __builtin_amdgcn_permlane32_swap(pk2(P[10], P[11]), pk2(P[14], P[15]), false, false);
            B[0] = r0[0]; B[1] = r1[0]; B[2] = r0[1]; B[3] = r1[1];
        }
        w0 = __builtin_bit_cast(bf16x8, A);
        w1 = __builtin_bit_cast(bf16x8, B);
    };
    auto tsum = [](const f32x16& P) -> float {
        float s0 = (P[0] + P[1]) + (P[2] + P[3]);
        float s1 = (P[4] + P[5]) + (P[6] + P[7]);
        float s2 = (P[8] + P[9]) + (P[10] + P[11]);
        float s3 = (P[12] + P[13]) + (P[14] + P[15]);
        return (s0 + s1) + (s2 + s3);
    };

    bf16x8 pw[4];

    // ---- iter 0: QK(0), exp, pack (no PV yet) ----
    {
        f32x16 C0, C1;
        #pragma unroll
        for (int r = 0; r < 16; r++) { C0[r] = 0.f; C1[r] = 0.f; }
        #pragma unroll
        for (int c = 0; c < 4; c++) {
            C0 = __builtin_amdgcn_mfma_f32_32x32x16_bf16(ldKf(0, 0, c), qf[c], C0, 0, 0, 0);
            C1 = __builtin_amdgcn_mfma_f32_32x32x16_bf16(ldKf(0, 1, c), qf[c], C1, 0, 0, 0);
        }
        #pragma unroll
        for (int r = 0; r < 16; r++) {
            C0[r] = __builtin_amdgcn_exp2f(C0[r]);
            C1[r] = __builtin_amdgcn_exp2f(C1[r]);
        }
        lsum += tsum(C0) + tsum(C1);
        packP(C0, pw[0], pw[1]);
        packP(C1, pw[2], pw[3]);
    }

    // ---- steady state: QK(t) + PV(t-1) back-to-back, then exp/sum/pack ----
    #pragma unroll 2
    for (int t = 1; t < 16; t++) {
        f32x16 C0, C1;
        #pragma unroll
        for (int r = 0; r < 16; r++) { C0[r] = 0.f; C1[r] = 0.f; }
        #pragma unroll
        for (int c = 0; c < 4; c++) {
            C0 = __builtin_amdgcn_mfma_f32_32x32x16_bf16(ldKf(t, 0, c), qf[c], C0, 0, 0, 0);
            C1 = __builtin_amdgcn_mfma_f32_32x32x16_bf16(ldKf(t, 1, c), qf[c], C1, 0, 0, 0);
        }
        #pragma unroll
        for (int dt = 0; dt < 2; dt++) {
            #pragma unroll
            for (int nc = 0; nc < 4; nc++) {
                accO[dt] = __builtin_amdgcn_mfma_f32_32x32x16_bf16(
                    ldVf(t - 1, dt, nc), pw[nc], accO[dt], 0, 0, 0);
            }
        }

        #pragma unroll
        for (int r = 0; r < 16; r++) {
            C0[r] = __builtin_amdgcn_exp2f(C0[r]);
            C1[r] = __builtin_amdgcn_exp2f(C1[r]);
        }
        lsum += tsum(C0) + tsum(C1);
        packP(C0, pw[0], pw[1]);
        packP(C1, pw[2], pw[3]);
    }

    // ---- epilogue: PV(15) ----
    #pragma unroll
    for (int dt = 0; dt < 2; dt++) {
        #pragma unroll
        for (int nc = 0; nc < 4; nc++) {
            accO[dt] = __builtin_amdgcn_mfma_f32_32x32x16_bf16(
                ldVf(15, dt, nc), pw[nc], accO[dt], 0, 0, 0);
        }
    }

    float inv = 1.0f / (lsum + __shfl_xor(lsum, 32));
    int b = bh >> 4, hd = bh & 15;
    int rowblk = b * 32 + qt * 4 + wave;  // (b*1024 + qbase) >> 5
    #pragma unroll
    for (int dt = 0; dt < 2; dt++)
        #pragma unroll
        for (int rg = 0; rg < 4; rg++) {
            int g = (hd * 4 + dt * 2 + (rg >> 1)) * 2 + (rg & 1);
            uint2 val;
            val.x = pk2(accO[dt][rg * 4 + 0] * inv, accO[dt][rg * 4 + 1] * inv);
            val.y = pk2(accO[dt][rg * 4 + 2] * inv, accO[dt][rg * 4 + 3] * inv);
            *(uint2*)((char*)attnF + ((size_t)rowblk * 4096 + g * 32 + l31) * 16 + hi * 8) = val;
        }
}

// ---------------- out projection v4: regrid for full-CU coverage ----------------
__global__ __launch_bounds__(192, 2) void k_out(
    const unsigned short* __restrict__ attnF, const unsigned short* __restrict__ woF,
    const float* __restrict__ bias, float* __restrict__ out) {
    int wave = threadIdx.x >> 6, lane = threadIdx.x & 63;
    int l31 = lane & 31, hi = lane >> 5;
    int W = blockIdx.x * 3 + wave;   // 0..1535
    int nb = W / 6, cb = W % 6;      // 256 n-blocks x 6 c-blocks
    const unsigned short* A = attnF + (size_t)nb * 4096 * 8;
    const unsigned short* B = woF + (size_t)cb * 4096 * 8;

    f32x16 acc0, acc1;
    #pragma unroll
    for (int r = 0; r < 16; r++) { acc0[r] = 0.f; acc1[r] = 0.f; }
    #pragma unroll 8
    for (int kc = 0; kc < 32; kc++) {
        bf16x8 a0 = *(const bf16x8*)(A + (((2 * kc) * 2 + hi) * 32 + l31) * 8);
        bf16x8 b0 = *(const bf16x8*)(B + (((2 * kc) * 2 + hi) * 32 + l31) * 8);
        bf16x8 a1 = *(const bf16x8*)(A + (((2 * kc + 1) * 2 + hi) * 32 + l31) * 8);
        bf16x8 b1 = *(const bf16x8*)(B + (((2 * kc + 1) * 2 + hi) * 32 + l31) * 8);
        acc0 = __builtin_amdgcn_mfma_f32_32x32x16_bf16(a0, b0, acc0, 0, 0, 0);
        acc1 = __builtin_amdgcn_mfma_f32_32x32x16_bf16(a1, b1, acc1, 0, 0, 0);
    }
    float bi = bias[cb * 32 + l31];
    #pragma unroll
    for (int r = 0; r < 16; r++) {
        int n = nb * 32 + (r & 3) + 8 * (r >> 2) + 4 * hi;
        out[(size_t)n * DIM + cb * 32 + l31] = acc0[r] + acc1[r] + bi;
    }
}

extern "C" void kernel_launch(void* const* d_in, const int* in_sizes, int n_in,
                              void* d_out, int out_size, void* d_ws, size_t ws_size,
                              hipStream_t stream) {
    const float* x     = (const float*)d_in[0];
    const float* shift = (const float*)d_in[1];
    const float* scale = (const float*)d_in[2];
    const float* nw    = (const float*)d_in[3];
    const float* nbv   = (const float*)d_in[4];
    const float* wqkv  = (const float*)d_in[5];
    const float* wout  = (const float*)d_in[6];
    const float* bout  = (const float*)d_in[7];
    float* out = (float*)d_out;

    char* ws = (char*)d_ws;
    unsigned short* hF    = (unsigned short*)(ws + 0);
    unsigned short* wF    = (unsigned short*)(ws + 3145728);
    unsigned short* woF   = (unsigned short*)(ws + 3145728 + 1179648);
    unsigned short* qmF   = (unsigned short*)(ws + 4718592);
    unsigned short* kmF   = (unsigned short*)(ws + 4718592 + 16777216);
    unsigned short* vtF   = (unsigned short*)(ws + 4718592 + 2 * 16777216);
    unsigned short* attnF = (unsigned short*)(ws + 4718592 + 3 * 16777216);

    k_pre<<<dim3(5120), dim3(256), 0, stream>>>(x, shift, scale, nw, nbv, wqkv, wout, hF, wF, woF);
    k_qkv<<<dim3(48, 64), dim3(256), 0, stream>>>(hF, wF, qmF, kmF, vtF);
    k_attn<<<dim3(128, 8), dim3(256), 0, stream>>>(qmF, kmF, vtF, attnF);
    k_out<<<dim3(512), dim3(192), 0, stream>>>(attnF, woF, bout, out);
}

// Round 23
// 89.954 us; speedup vs baseline: 1.7716x; 1.7716x over previous
//
#include <hip/hip_runtime.h>

#define DIM 192
#define NB 8
#define NTOK 1024
#define HEADS 16
#define DH 64
#define INNER 1024
#define ROWS (NB * NTOK)  // 8192

typedef __bf16 bf16x8 __attribute__((ext_vector_type(8)));
typedef float f32x4 __attribute__((ext_vector_type(4)));
typedef float f32x16 __attribute__((ext_vector_type(16)));
typedef unsigned int u32x4 __attribute__((ext_vector_type(4)));

__device__ inline unsigned short f2bf(float f) {
    union { float f; unsigned u; } v; v.f = f;
    unsigned r = v.u + 0x7FFF + ((v.u >> 16) & 1);
    return (unsigned short)(r >> 16);
}

__device__ inline unsigned pk2(float a, float b) {
    __bf16 x = (__bf16)a, y = (__bf16)b;
    unsigned short ux = __builtin_bit_cast(unsigned short, x);
    unsigned short uy = __builtin_bit_cast(unsigned short, y);
    return (unsigned)ux | ((unsigned)uy << 16);
}

// fragment-major index for a [*][depth] bf16 operand consumed as 32x32x16
__device__ inline size_t fragIdx(int row, int k, int depth) {
    return ((size_t)(row >> 5) * ((size_t)depth * 4) +
            (size_t)(((k >> 4) * 2 + ((k >> 3) & 1)) * 32 + (row & 31))) * 8 + (k & 7);
}

// ---------------- fused preprocessing ----------------
__global__ __launch_bounds__(256) void k_pre(
    const float* __restrict__ x, const float* __restrict__ shift,
    const float* __restrict__ scale, const float* __restrict__ nw,
    const float* __restrict__ nb, const float* __restrict__ wqkv,
    const float* __restrict__ wout,
    unsigned short* __restrict__ hF, unsigned short* __restrict__ wF,
    unsigned short* __restrict__ woF) {
    int bid = blockIdx.x;
    if (bid < 2048) {
        int row = bid * 4 + (threadIdx.x >> 6);
        int lane = threadIdx.x & 63;
        const float* xr = x + row * DIM;
        float v0 = xr[lane], v1 = xr[lane + 64], v2 = xr[lane + 128];
        float s = v0 + v1 + v2;
        #pragma unroll
        for (int m = 1; m < 64; m <<= 1) s += __shfl_xor(s, m);
        float mean = s * (1.0f / DIM);
        float d0 = v0 - mean, d1 = v1 - mean, d2 = v2 - mean;
        float q = d0 * d0 + d1 * d1 + d2 * d2;
        #pragma unroll
        for (int m = 1; m < 64; m <<= 1) q += __shfl_xor(q, m);
        float rs = rsqrtf(q * (1.0f / DIM) + 1e-5f);
        int b = row >> 10;
        float vv[3] = {v0, v1, v2};
        #pragma unroll
        for (int i = 0; i < 3; i++) {
            int d = lane + 64 * i;
            float val = (vv[i] - mean) * rs * nw[d] + nb[d];
            val = val * (1.0f + scale[b * DIM + d]) + shift[b * DIM + d];
            hF[fragIdx(row, d, DIM)] = f2bf(val);
        }
    } else if (bid < 4352) {
        int idx = (bid - 2048) * 256 + threadIdx.x;  // < 192*3072
        int k = idx / 3072, c = idx % 3072;
        wF[fragIdx(c, k, DIM)] = f2bf(wqkv[idx]);
    } else {
        int idx = (bid - 4352) * 256 + threadIdx.x;  // < 1024*192
        int k = idx / 192, c = idx % 192;
        woF[fragIdx(c, k, INNER)] = f2bf(wout[idx]);
    }
}

// ---------------- QKV GEMM v5: fragment-major in AND out ----------------
__global__ __launch_bounds__(256, 3) void k_qkv(
    const unsigned short* __restrict__ hF, const unsigned short* __restrict__ wF,
    unsigned short* __restrict__ qmF, unsigned short* __restrict__ kmF,
    unsigned short* __restrict__ vtF) {
    const float QSC = 0.125f * 1.4426950408889634f;
    int tid = threadIdx.x;
    int wave = tid >> 6, lane = tid & 63;
    int l31 = lane & 31, hi = lane >> 5;
    int c0 = blockIdx.x * 64 + (wave >> 1) * 32;
    int typ = c0 >> 10;              // 0=Q 1=K 2=V
    int hd  = (c0 & 1023) >> 6;      // head
    int coff = c0 & 32;              // 32-channel tile within head panel

    const unsigned short* Ab = wF + (size_t)(c0 >> 5) * 768 * 8;
    bf16x8 af[12];
    #pragma unroll
    for (int kc = 0; kc < 12; kc++)
        af[kc] = *(const bf16x8*)(Ab + ((kc * 2 + hi) * 32 + l31) * 8);

    #pragma unroll
    for (int ns = 0; ns < 2; ns++) {
        int n0 = blockIdx.y * 128 + (wave & 1) * 64 + ns * 32;
        const unsigned short* Bb = hF + (size_t)(n0 >> 5) * 768 * 8;
        f32x16 acc0, acc1;
        #pragma unroll
        for (int r = 0; r < 16; r++) { acc0[r] = 0.f; acc1[r] = 0.f; }
        if (typ < 2) {
            #pragma unroll
            for (int kc = 0; kc < 6; kc++) {
                bf16x8 bf0 = *(const bf16x8*)(Bb + (((2 * kc) * 2 + hi) * 32 + l31) * 8);
                bf16x8 bf1 = *(const bf16x8*)(Bb + (((2 * kc + 1) * 2 + hi) * 32 + l31) * 8);
                acc0 = __builtin_amdgcn_mfma_f32_32x32x16_bf16(af[2 * kc], bf0, acc0, 0, 0, 0);
                acc1 = __builtin_amdgcn_mfma_f32_32x32x16_bf16(af[2 * kc + 1], bf1, acc1, 0, 0, 0);
            }
        } else {
            // V: swap operands so D-lane = channel (d), D-regs = token (n)
            #pragma unroll
            for (int kc = 0; kc < 6; kc++) {
                bf16x8 bf0 = *(const bf16x8*)(Bb + (((2 * kc) * 2 + hi) * 32 + l31) * 8);
                bf16x8 bf1 = *(const bf16x8*)(Bb + (((2 * kc + 1) * 2 + hi) * 32 + l31) * 8);
                acc0 = __builtin_amdgcn_mfma_f32_32x32x16_bf16(bf0, af[2 * kc], acc0, 0, 0, 0);
                acc1 = __builtin_amdgcn_mfma_f32_32x32x16_bf16(bf1, af[2 * kc + 1], acc1, 0, 0, 0);
            }
        }
        f32x16 acc;
        #pragma unroll
        for (int r = 0; r < 16; r++) acc[r] = acc0[r] + acc1[r];

        int bb = n0 >> 10, nm = n0 & 1023;
        int tt = nm >> 6;
        unsigned short* base;
        if (typ == 0) base = qmF + (size_t)(bb * 16 + hd) * 65536;
        else if (typ == 1) base = kmF + (size_t)(bb * 16 + hd) * 65536;
        else base = vtF + (size_t)(bb * 16 + hd) * 65536;

        if (typ < 2) {
            float sc = (typ == 0) ? QSC : 1.0f;
            int rowgrp = (nm >> 5) & 1;
            #pragma unroll
            for (int rg = 0; rg < 4; rg++) {
                int ob = coff + rg * 8;   // d-octet base
                int g = (rowgrp * 4 + (ob >> 4)) * 2 + ((ob >> 3) & 1);
                uint2 val;
                val.x = pk2(acc[rg * 4 + 0] * sc, acc[rg * 4 + 1] * sc);
                val.y = pk2(acc[rg * 4 + 2] * sc, acc[rg * 4 + 3] * sc);
                *(uint2*)(base + (tt * 16 + g) * 256 + l31 * 8 + hi * 4) = val;
            }
        } else {
            int drg = coff >> 5;
            #pragma unroll
            for (int rg = 0; rg < 4; rg++) {
                int nb2 = (nm & 32) + rg * 8;  // n-octet base within tile
                int g = (drg * 4 + (nb2 >> 4)) * 2 + ((nb2 >> 3) & 1);
                uint2 val;
                val.x = pk2(acc[rg * 4 + 0], acc[rg * 4 + 1]);
                val.y = pk2(acc[rg * 4 + 2], acc[rg * 4 + 3]);
                *(uint2*)(base + (tt * 16 + g) * 256 + l31 * 8 + hi * 4) = val;
            }
        }
    }
}

// ---------------- flash attention v12: LDS-free fragment-major (session optimum) ----------------
// grid (128 bh, 8 qt) x 256 thr (4 waves). Coalesced 16B/lane fragment reads
// from L2; zero-max softmax; QK(t)+PV(t-1) register pipeline; no LDS/barriers.
// NOTE: single C-tile in flight is a hard constraint — any 2-deep schedule
// (hand pipeline r16, counted-vmcnt r10, unroll-2 r22) spills 2-10x.
__global__ __launch_bounds__(256, 3) void k_attn(
    const unsigned short* __restrict__ qmF, const unsigned short* __restrict__ kmF,
    const unsigned short* __restrict__ vtF, unsigned short* __restrict__ attnF) {
    int tid = threadIdx.x;
    int wave = tid >> 6, lane = tid & 63;
    int l31 = lane & 31, hi = lane >> 5;
    int bh = blockIdx.x, qt = blockIdx.y;
    int qbase = qt * 128 + wave * 32;
    const unsigned short* Qb = qmF + (size_t)bh * 65536;
    const unsigned short* Kb = kmF + (size_t)bh * 65536;
    const unsigned short* Vb = vtF + (size_t)bh * 65536;

    int tq = qbase >> 6, rq = (qbase >> 5) & 1;
    bf16x8 qf[4];
    #pragma unroll
    for (int c = 0; c < 4; c++)
        qf[c] = *(const bf16x8*)(Qb + (tq * 16 + (rq * 4 + c) * 2 + hi) * 256 + l31 * 8);

    float lsum = 0.f;
    f32x16 accO[2];
    #pragma unroll
    for (int r = 0; r < 16; r++) { accO[0][r] = 0.f; accO[1][r] = 0.f; }

    auto ldKf = [&](int t, int rowgrp, int c) -> bf16x8 {
        return *(const bf16x8*)(Kb + (t * 16 + (rowgrp * 4 + c) * 2 + hi) * 256 + l31 * 8);
    };
    auto ldVf = [&](int t, int dt, int nc) -> bf16x8 {
        return *(const bf16x8*)(Vb + (t * 16 + (dt * 4 + nc) * 2 + hi) * 256 + l31 * 8);
    };
    auto packP = [&](const f32x16& P, bf16x8& w0, bf16x8& w1) {
        u32x4 A, B;
        {
            auto r0 = __builtin_amdgcn_permlane32_swap(pk2(P[0], P[1]), pk2(P[4], P[5]), false, false);
            auto r1 = __builtin_amdgcn_permlane32_swap(pk2(P[2], P[3]), pk2(P[6], P[7]), false, false);
            A[0] = r0[0]; A[1] = r1[0]; A[2] = r0[1]; A[3] = r1[1];
        }
        {
            auto r0 = __builtin_amdgcn_permlane32_swap(pk2(P[8], P[9]), pk2(P[12], P[13]), false, false);
            auto r1 = __builtin_amdgcn_permlane32_swap(pk2(P[10], P[11]), pk2(P[14], P[15]), false, false);
            B[0] = r0[0]; B[1] = r1[0]; B[2] = r0[1]; B[3] = r1[1];
        }
        w0 = __builtin_bit_cast(bf16x8, A);
        w1 = __builtin_bit_cast(bf16x8, B);
    };
    auto tsum = [](const f32x16& P) -> float {
        float s0 = (P[0] + P[1]) + (P[2] + P[3]);
        float s1 = (P[4] + P[5]) + (P[6] + P[7]);
        float s2 = (P[8] + P[9]) + (P[10] + P[11]);
        float s3 = (P[12] + P[13]) + (P[14] + P[15]);
        return (s0 + s1) + (s2 + s3);
    };

    bf16x8 pw[4];

    // ---- iter 0: QK(0), exp, pack (no PV yet) ----
    {
        f32x16 C0, C1;
        #pragma unroll
        for (int r = 0; r < 16; r++) { C0[r] = 0.f; C1[r] = 0.f; }
        #pragma unroll
        for (int c = 0; c < 4; c++) {
            C0 = __builtin_amdgcn_mfma_f32_32x32x16_bf16(ldKf(0, 0, c), qf[c], C0, 0, 0, 0);
            C1 = __builtin_amdgcn_mfma_f32_32x32x16_bf16(ldKf(0, 1, c), qf[c], C1, 0, 0, 0);
        }
        #pragma unroll
        for (int r = 0; r < 16; r++) {
            C0[r] = __builtin_amdgcn_exp2f(C0[r]);
            C1[r] = __builtin_amdgcn_exp2f(C1[r]);
        }
        lsum += tsum(C0) + tsum(C1);
        packP(C0, pw[0], pw[1]);
        packP(C1, pw[2], pw[3]);
    }

    // ---- steady state: QK(t) + PV(t-1) back-to-back, then exp/sum/pack ----
    for (int t = 1; t < 16; t++) {
        f32x16 C0, C1;
        #pragma unroll
        for (int r = 0; r < 16; r++) { C0[r] = 0.f; C1[r] = 0.f; }
        #pragma unroll
        for (int c = 0; c < 4; c++) {
            C0 = __builtin_amdgcn_mfma_f32_32x32x16_bf16(ldKf(t, 0, c), qf[c], C0, 0, 0, 0);
            C1 = __builtin_amdgcn_mfma_f32_32x32x16_bf16(ldKf(t, 1, c), qf[c], C1, 0, 0, 0);
        }
        #pragma unroll
        for (int dt = 0; dt < 2; dt++) {
            #pragma unroll
            for (int nc = 0; nc < 4; nc++) {
                accO[dt] = __builtin_amdgcn_mfma_f32_32x32x16_bf16(
                    ldVf(t - 1, dt, nc), pw[nc], accO[dt], 0, 0, 0);
            }
        }

        #pragma unroll
        for (int r = 0; r < 16; r++) {
            C0[r] = __builtin_amdgcn_exp2f(C0[r]);
            C1[r] = __builtin_amdgcn_exp2f(C1[r]);
        }
        lsum += tsum(C0) + tsum(C1);
        packP(C0, pw[0], pw[1]);
        packP(C1, pw[2], pw[3]);
    }

    // ---- epilogue: PV(15) ----
    #pragma unroll
    for (int dt = 0; dt < 2; dt++) {
        #pragma unroll
        for (int nc = 0; nc < 4; nc++) {
            accO[dt] = __builtin_amdgcn_mfma_f32_32x32x16_bf16(
                ldVf(15, dt, nc), pw[nc], accO[dt], 0, 0, 0);
        }
    }

    float inv = 1.0f / (lsum + __shfl_xor(lsum, 32));
    int b = bh >> 4, hd = bh & 15;
    int rowblk = b * 32 + qt * 4 + wave;  // (b*1024 + qbase) >> 5
    #pragma unroll
    for (int dt = 0; dt < 2; dt++)
        #pragma unroll
        for (int rg = 0; rg < 4; rg++) {
            int g = (hd * 4 + dt * 2 + (rg >> 1)) * 2 + (rg & 1);
            uint2 val;
            val.x = pk2(accO[dt][rg * 4 + 0] * inv, accO[dt][rg * 4 + 1] * inv);
            val.y = pk2(accO[dt][rg * 4 + 2] * inv, accO[dt][rg * 4 + 3] * inv);
            *(uint2*)((char*)attnF + ((size_t)rowblk * 4096 + g * 32 + l31) * 16 + hi * 8) = val;
        }
}

// ---------------- out projection v4: regrid for full-CU coverage ----------------
__global__ __launch_bounds__(192, 2) void k_out(
    const unsigned short* __restrict__ attnF, const unsigned short* __restrict__ woF,
    const float* __restrict__ bias, float* __restrict__ out) {
    int wave = threadIdx.x >> 6, lane = threadIdx.x & 63;
    int l31 = lane & 31, hi = lane >> 5;
    int W = blockIdx.x * 3 + wave;   // 0..1535
    int nb = W / 6, cb = W % 6;      // 256 n-blocks x 6 c-blocks
    const unsigned short* A = attnF + (size_t)nb * 4096 * 8;
    const unsigned short* B = woF + (size_t)cb * 4096 * 8;

    f32x16 acc0, acc1;
    #pragma unroll
    for (int r = 0; r < 16; r++) { acc0[r] = 0.f; acc1[r] = 0.f; }
    #pragma unroll 8
    for (int kc = 0; kc < 32; kc++) {
        bf16x8 a0 = *(const bf16x8*)(A + (((2 * kc) * 2 + hi) * 32 + l31) * 8);
        bf16x8 b0 = *(const bf16x8*)(B + (((2 * kc) * 2 + hi) * 32 + l31) * 8);
        bf16x8 a1 = *(const bf16x8*)(A + (((2 * kc + 1) * 2 + hi) * 32 + l31) * 8);
        bf16x8 b1 = *(const bf16x8*)(B + (((2 * kc + 1) * 2 + hi) * 32 + l31) * 8);
        acc0 = __builtin_amdgcn_mfma_f32_32x32x16_bf16(a0, b0, acc0, 0, 0, 0);
        acc1 = __builtin_amdgcn_mfma_f32_32x32x16_bf16(a1, b1, acc1, 0, 0, 0);
    }
    float bi = bias[cb * 32 + l31];
    #pragma unroll
    for (int r = 0; r < 16; r++) {
        int n = nb * 32 + (r & 3) + 8 * (r >> 2) + 4 * hi;
        out[(size_t)n * DIM + cb * 32 + l31] = acc0[r] + acc1[r] + bi;
    }
}

extern "C" void kernel_launch(void* const* d_in, const int* in_sizes, int n_in,
                              void* d_out, int out_size, void* d_ws, size_t ws_size,
                              hipStream_t stream) {
    const float* x     = (const float*)d_in[0];
    const float* shift = (const float*)d_in[1];
    const float* scale = (const float*)d_in[2];
    const float* nw    = (const float*)d_in[3];
    const float* nbv   = (const float*)d_in[4];
    const float* wqkv  = (const float*)d_in[5];
    const float* wout  = (const float*)d_in[6];
    const float* bout  = (const float*)d_in[7];
    float* out = (float*)d_out;

    char* ws = (char*)d_ws;
    unsigned short* hF    = (unsigned short*)(ws + 0);
    unsigned short* wF    = (unsigned short*)(ws + 3145728);
    unsigned short* woF   = (unsigned short*)(ws + 3145728 + 1179648);
    unsigned short* qmF   = (unsigned short*)(ws + 4718592);
    unsigned short* kmF   = (unsigned short*)(ws + 4718592 + 16777216);
    unsigned short* vtF   = (unsigned short*)(ws + 4718592 + 2 * 16777216);
    unsigned short* attnF = (unsigned short*)(ws + 4718592 + 3 * 16777216);

    k_pre<<<dim3(5120), dim3(256), 0, stream>>>(x, shift, scale, nw, nbv, wqkv, wout, hF, wF, woF);
    k_qkv<<<dim3(48, 64), dim3(256), 0, stream>>>(hF, wF, qmF, kmF, vtF);
    k_attn<<<dim3(128, 8), dim3(256), 0, stream>>>(qmF, kmF, vtF, attnF);
    k_out<<<dim3(512), dim3(192), 0, stream>>>(attnF, woF, bout, out);
}